// Round 20
// baseline (401.537 us; speedup 1.0000x reference)
//
#include <hip/hip_runtime.h>
#include <hip/hip_bf16.h>
#include <hip/hip_fp16.h>
#include <math.h>

// HEAT layer. Round 19 (resubmit): (1) GEMM epilogues in two 64-col half-passes
// (LDS 33->17KB, occupancy 4->8 blocks/CU); (2) edge_agg3 4-edge ILP.
// Structure otherwise = round 18 anchor (396us).

#define NDIM 128
#define NRNG 32
#define NBK 512
#define UNITS (NBK * 4)
#define HSPAN 2048

typedef __attribute__((ext_vector_type(8))) short short8;
typedef __attribute__((ext_vector_type(4))) float f32x4;
typedef __attribute__((ext_vector_type(2))) _Float16 half2v;

__device__ __forceinline__ float bf2f(unsigned short u) {
    union { unsigned int i; float f; } x; x.i = ((unsigned int)u) << 16; return x.f;
}
__device__ __forceinline__ unsigned short f2bf(float f) {
    unsigned int u = __float_as_uint(f);
    unsigned int r = (u + 0x7FFFu + ((u >> 16) & 1u)) >> 16;   // RNE
    return (unsigned short)r;
}
__device__ __forceinline__ int range_of(int d, int n) {
    return (int)(((long long)d * NRNG) / n);
}
union U4h { ushort4 u; struct { half2v a, b; } h; };

// ---------------- weight prep: 8 mats f32[k][n] -> bf16 [n][k], LDS transpose ----------------
__global__ __launch_bounds__(256) void wt_prep(const float* __restrict__ Kw, const float* __restrict__ Qw,
                                               const float* __restrict__ Vw, const float* __restrict__ Aw,
                                               unsigned short* __restrict__ Wtbuf)
{
    const int b = blockIdx.x;        // t*4 + m
    const int t = b >> 2, m = b & 3;
    const float* src = (m == 0 ? Kw : m == 1 ? Qw : m == 2 ? Vw : Aw) + (size_t)t * 16384;
    unsigned short* dst = Wtbuf + (size_t)b * 16384;
    const int tid = threadIdx.x;
    __shared__ float tile[64][132];
#pragma unroll
    for (int h = 0; h < 2; ++h) {
        const int k0 = h * 64;
        for (int idx = tid; idx < 64 * 32; idx += 256) {
            const int kr = idx >> 5;
            const int c4 = (idx & 31) * 4;
            const float4 v = *(const float4*)(src + (size_t)(k0 + kr) * 128 + c4);
            tile[kr][c4 + 0] = v.x; tile[kr][c4 + 1] = v.y;
            tile[kr][c4 + 2] = v.z; tile[kr][c4 + 3] = v.w;
        }
        __syncthreads();
        for (int idx = tid; idx < 128 * 16; idx += 256) {
            const int nn = idx >> 4;
            const int kk4 = (idx & 15) * 4;
            ushort4 o;
            o.x = f2bf(tile[kk4 + 0][nn]); o.y = f2bf(tile[kk4 + 1][nn]);
            o.z = f2bf(tile[kk4 + 2][nn]); o.w = f2bf(tile[kk4 + 3][nn]);
            *(ushort4*)(dst + (size_t)nn * 128 + k0 + kk4) = o;
        }
        __syncthreads();
    }
}

// ---------------- fused K/Q/V MFMA GEMM (K,Q out fp16; V out bf16), half-width epilogue ----------------
__global__ __launch_bounds__(256) void gemm_kqv(
    const float* __restrict__ feat0, const float* __restrict__ feat1,
    const unsigned short* __restrict__ Wtbuf,
    const float* __restrict__ Kb, const float* __restrict__ Qb, const float* __restrict__ Vb,
    unsigned short* __restrict__ K0o, unsigned short* __restrict__ Q0o, unsigned short* __restrict__ V0o,
    unsigned short* __restrict__ K1o, unsigned short* __restrict__ Q1o, unsigned short* __restrict__ V1o,
    int n0, int n1, int blocks0)
{
    const int b = blockIdx.x;
    const bool t1 = (b >= blocks0);
    const float* feat = t1 ? feat1 : feat0;
    const int n = t1 ? n1 : n0;
    const int boff = t1 ? NDIM : 0;
    const unsigned short* Wt = Wtbuf + (t1 ? 4 * 16384 : 0);
    unsigned short* outs[3];
    outs[0] = t1 ? K1o : K0o; outs[1] = t1 ? Q1o : Q0o; outs[2] = t1 ? V1o : V0o;
    const float* biases[3] = {Kb + boff, Qb + boff, Vb + boff};

    const int tid = threadIdx.x;
    const int w = tid >> 6, lane = tid & 63;
    const int r16 = lane & 15, kg = lane >> 4;
    const int brow = (t1 ? b - blocks0 : b) * 64;
    const int arow = min(brow + w * 16 + r16, n - 1);

    __shared__ float sacc[64][66];

    short8 afr[4];
#pragma unroll
    for (int k0i = 0; k0i < 4; ++k0i) {
        const float* ap = feat + (size_t)arow * NDIM + k0i * 32 + kg * 8;
        const float4 lo = *(const float4*)ap;
        const float4 hi = *(const float4*)(ap + 4);
        short8 a;
        a[0] = (short)f2bf(lo.x); a[1] = (short)f2bf(lo.y);
        a[2] = (short)f2bf(lo.z); a[3] = (short)f2bf(lo.w);
        a[4] = (short)f2bf(hi.x); a[5] = (short)f2bf(hi.y);
        a[6] = (short)f2bf(hi.z); a[7] = (short)f2bf(hi.w);
        afr[k0i] = a;
    }
    const int c4 = (lane & 15) * 4;          // 4-col slot within a 64-col half
#pragma unroll
    for (int m = 0; m < 3; ++m) {
        const unsigned short* wt = Wt + (size_t)m * 16384;
        f32x4 acc[8];
#pragma unroll
        for (int c = 0; c < 8; ++c) acc[c] = (f32x4){0.f, 0.f, 0.f, 0.f};
#pragma unroll
        for (int k0i = 0; k0i < 4; ++k0i)
#pragma unroll
            for (int c = 0; c < 8; ++c) {
                const short8 bb = *(const short8*)(wt + (size_t)(16 * c + r16) * NDIM + k0i * 32 + kg * 8);
                acc[c] = __builtin_amdgcn_mfma_f32_16x16x32_bf16(afr[k0i], bb, acc[c], 0, 0, 0);
            }
#pragma unroll
        for (int h = 0; h < 2; ++h) {
            __syncthreads();
#pragma unroll
            for (int cl = 0; cl < 4; ++cl)
#pragma unroll
                for (int j = 0; j < 4; ++j)
                    sacc[w * 16 + kg * 4 + j][16 * cl + r16] = acc[h * 4 + cl][j];
            __syncthreads();
            const float4 b4 = *(const float4*)(biases[m] + h * 64 + c4);
            const float bias4[4] = {b4.x, b4.y, b4.z, b4.w};
#pragma unroll
            for (int j = 0; j < 4; ++j) {
                const int rloc = w * 16 + (lane >> 4) + j * 4;
                const int grow = brow + rloc;
                if (grow < n) {
                    ushort4 o;
#pragma unroll
                    for (int i = 0; i < 4; ++i) {
                        const float x = sacc[rloc][c4 + i] + bias4[i];
                        ((unsigned short*)&o)[i] =
                            (m < 2) ? __half_as_ushort(__float2half(x)) : f2bf(x);
                    }
                    *(ushort4*)(outs[m] + (size_t)grow * NDIM + h * 64 + c4) = o;
                }
            }
        }
    }
}

// ---------------- fused output MFMA GEMM, half-width epilogue ----------------
__global__ __launch_bounds__(256) void gemm_out(
    const unsigned short* __restrict__ aggb0a, const unsigned short* __restrict__ aggb0b,
    const unsigned short* __restrict__ aggb1,
    const unsigned short* __restrict__ Wtbuf, const float* __restrict__ Ab,
    const float* __restrict__ feat0, const float* __restrict__ feat1,
    const float* __restrict__ skip, float* __restrict__ out,
    int n0, int n1, int blocks0)
{
    const int b = blockIdx.x;
    const bool t1 = (b >= blocks0);
    const int n = t1 ? n1 : n0;
    const unsigned short* A1 = t1 ? aggb1 : aggb0a;
    const unsigned short* A2 = t1 ? (const unsigned short*)nullptr : aggb0b;
    const unsigned short* Wt = Wtbuf + (t1 ? 7 : 3) * 16384;
    const float* bias = Ab + (t1 ? NDIM : 0);
    const float* feat = t1 ? feat1 : feat0;
    float* C = out + (t1 ? (size_t)n0 * NDIM : 0);
    const int nid = t1 ? 1 : 0;

    const int tid = threadIdx.x;
    const int w = tid >> 6, lane = tid & 63;
    const int r16 = lane & 15, kg = lane >> 4;
    const int brow = (t1 ? b - blocks0 : b) * 64;
    const int arow = min(brow + w * 16 + r16, n - 1);

    __shared__ float sacc[64][66];

    short8 afr[4];
#pragma unroll
    for (int k0i = 0; k0i < 4; ++k0i) {
        short8 a = *(const short8*)(A1 + (size_t)arow * NDIM + k0i * 32 + kg * 8);
        if (!t1) {
            const short8 bb = *(const short8*)(A2 + (size_t)arow * NDIM + k0i * 32 + kg * 8);
#pragma unroll
            for (int j = 0; j < 8; ++j) {
                const float v = 0.5f * (bf2f((unsigned short)a[j]) + bf2f((unsigned short)bb[j]));
                a[j] = (short)f2bf(v);
            }
        }
        afr[k0i] = a;
    }
    f32x4 acc[8];
#pragma unroll
    for (int c = 0; c < 8; ++c) acc[c] = (f32x4){0.f, 0.f, 0.f, 0.f};
#pragma unroll
    for (int k0i = 0; k0i < 4; ++k0i)
#pragma unroll
        for (int c = 0; c < 8; ++c) {
            const short8 bb = *(const short8*)(Wt + (size_t)(16 * c + r16) * NDIM + k0i * 32 + kg * 8);
            acc[c] = __builtin_amdgcn_mfma_f32_16x16x32_bf16(afr[k0i], bb, acc[c], 0, 0, 0);
        }
    const float sk = skip[nid];
    const float alpha = 1.f / (1.f + __expf(-sk));
    const float beta = 1.f - alpha;
    const int c4 = (lane & 15) * 4;
#pragma unroll
    for (int h = 0; h < 2; ++h) {
        __syncthreads();
#pragma unroll
        for (int cl = 0; cl < 4; ++cl)
#pragma unroll
            for (int j = 0; j < 4; ++j)
                sacc[w * 16 + kg * 4 + j][16 * cl + r16] = acc[h * 4 + cl][j];
        __syncthreads();
        const float4 b4 = *(const float4*)(bias + h * 64 + c4);
#pragma unroll
        for (int j = 0; j < 4; ++j) {
            const int rloc = w * 16 + (lane >> 4) + j * 4;
            const int grow = brow + rloc;
            if (grow < n) {
                const float4 f4 = *(const float4*)(feat + (size_t)grow * NDIM + h * 64 + c4);
                float4 o;
                o.x = (sacc[rloc][c4 + 0] + b4.x) * alpha + f4.x * beta;
                o.y = (sacc[rloc][c4 + 1] + b4.y) * alpha + f4.y * beta;
                o.z = (sacc[rloc][c4 + 2] + b4.z) * alpha + f4.z * beta;
                o.w = (sacc[rloc][c4 + 3] + b4.w) * alpha + f4.w * beta;
                *(float4*)(C + (size_t)grow * NDIM + h * 64 + c4) = o;
            }
        }
    }
}

// ---------------- phase A1: per-unit range counts ----------------
__global__ __launch_bounds__(256) void bucket_count(
    const int* __restrict__ d0, int E0, const int* __restrict__ d1, int E1,
    const int* __restrict__ d2, int E2, int n0, int n1, int* __restrict__ cnts)
{
    const int seg = blockIdx.y;
    const int* dst = seg == 0 ? d0 : (seg == 1 ? d1 : d2);
    const int E = seg == 0 ? E0 : (seg == 1 ? E1 : E2);
    const int ns = seg == 0 ? n1 : n0;
    const int unit = blockIdx.x * 4 + (threadIdx.x >> 6);
    const int lane = threadIdx.x & 63;
    const int span = (E + UNITS - 1) / UNITS;
    const int b = unit * span;
    const int e = min(b + span, E);

    int run[NRNG];
#pragma unroll
    for (int r0 = 0; r0 < NRNG; ++r0) run[r0] = 0;
    for (int i0 = b; i0 < e; i0 += 64) {
        const int i = i0 + lane;
        const bool v = i < e;
        const int d = v ? dst[i] : 0;
        const unsigned int r = v ? (unsigned int)range_of(d, ns) : 0xFFu;
#pragma unroll
        for (int r0 = 0; r0 < NRNG; ++r0)
            run[r0] += __popcll(__ballot(r == (unsigned int)r0));
    }
    if (lane == 0) {
        int* c = cnts + ((size_t)seg * UNITS + unit) * NRNG;
#pragma unroll
        for (int r0 = 0; r0 < NRNG; ++r0) c[r0] = run[r0];
    }
}

// ---------------- phase A2: exclusive scan of unit counts; totals -> rcur ----------------
__global__ __launch_bounds__(256) void bucket_scan(int* __restrict__ cnts, int* __restrict__ rcur)
{
    const int seg = blockIdx.x >> 5;
    const int r = blockIdx.x & 31;
    const int t = threadIdx.x, lane = t & 63, w = t >> 6;

    int v[8];
    int run = 0;
#pragma unroll
    for (int j = 0; j < 8; ++j) {
        const int u = t * 8 + j;
        const int x = cnts[((size_t)seg * UNITS + u) * NRNG + r];
        v[j] = run;
        run += x;
    }
    const int tsum = run;
    int x = tsum;
#pragma unroll
    for (int o = 1; o < 64; o <<= 1) {
        const int y = __shfl_up(x, o);
        if (lane >= o) x += y;
    }
    const int wexc = x - tsum;
    __shared__ int wsum[4];
    if (lane == 63) wsum[w] = x;
    __syncthreads();
    int wbase = 0;
    for (int i = 0; i < w; ++i) wbase += wsum[i];
    const int base = wbase + wexc;
#pragma unroll
    for (int j = 0; j < 8; ++j) {
        const int u = t * 8 + j;
        cnts[((size_t)seg * UNITS + u) * NRNG + r] = base + v[j];
    }
    if (t == 255) rcur[seg * NRNG + r] = base + tsum;
}

// ---------------- phase A3: deterministic staged write ----------------
__global__ __launch_bounds__(256) void bucket_write(
    const int* __restrict__ d0, const int* __restrict__ s0, const float* __restrict__ e0, int E0,
    const int* __restrict__ d1, const int* __restrict__ s1, const float* __restrict__ e1, int E1,
    const int* __restrict__ d2, const int* __restrict__ s2, const float* __restrict__ e2, int E2,
    int n0, int n1, const float* __restrict__ ew, const float* __restrict__ eb,
    const int* __restrict__ cnts, uint2* __restrict__ stg, int cap)
{
    const int seg = blockIdx.y;
    const int* dst = seg == 0 ? d0 : (seg == 1 ? d1 : d2);
    const int* src = seg == 0 ? s0 : (seg == 1 ? s1 : s2);
    const float* ev = seg == 0 ? e0 : (seg == 1 ? e1 : e2);
    const int E = seg == 0 ? E0 : (seg == 1 ? E1 : E2);
    const int ns = seg == 0 ? n1 : n0;
    const int unit = blockIdx.x * 4 + (threadIdx.x >> 6);
    const int lane = threadIdx.x & 63;
    const int span = (E + UNITS - 1) / UNITS;
    const int b = unit * span;
    const int e = min(b + span, E);
    const float LOG2E = 1.4426950408889634f;
    const float ews = ew[0] * 0.25f * LOG2E;
    const float ebs = eb[0] * 0.25f * LOG2E;
    uint2* sbase = stg + (size_t)seg * NRNG * cap;

    int run[NRNG];
    {
        const int* c = cnts + ((size_t)seg * UNITS + unit) * NRNG;
#pragma unroll
        for (int r0 = 0; r0 < NRNG; ++r0) run[r0] = c[r0];
    }
    for (int i0 = b; i0 < e; i0 += 64) {
        const int i = i0 + lane;
        const bool v = i < e;
        int d = 0, s = 0; float ee = 0.f;
        if (v) { d = dst[i]; s = src[i]; ee = ev[i]; }
        const unsigned int r = v ? (unsigned int)range_of(d, ns) : 0xFFu;
#pragma unroll
        for (int r0 = 0; r0 < NRNG; ++r0) {
            const unsigned long long m = __ballot(r == (unsigned int)r0);
            if (m == 0ull) continue;
            if (r == (unsigned int)r0) {
                const int off = run[r0] + __popcll(m & ((1ull << lane) - 1ull));
                sbase[(size_t)r0 * cap + off] =
                    make_uint2((unsigned int)d | ((unsigned int)s << 16), __float_as_uint(ee * ews + ebs));
            }
            run[r0] += __popcll(m);
        }
    }
}

// ---------------- phase B: per-range LDS counting sort -> off[] + edg[] (u32) ----------------
__global__ __launch_bounds__(1024) void sortB(
    const uint2* __restrict__ stg, int cap, const int* __restrict__ rcur,
    int nA, int* __restrict__ offA, unsigned int* __restrict__ gA,
    int nB, int* __restrict__ offB, unsigned int* __restrict__ gB,
    int nC, int* __restrict__ offC, unsigned int* __restrict__ gC)
{
    const int seg = blockIdx.y;
    const int r = blockIdx.x;
    const int n = seg == 0 ? nA : (seg == 1 ? nB : nC);
    int* off = seg == 0 ? offA : (seg == 1 ? offB : offC);
    unsigned int* edg = seg == 0 ? gA : (seg == 1 ? gB : gC);
    const int cnt = rcur[seg * NRNG + r];
    const uint2* s = stg + ((size_t)seg * NRNG + r) * cap;
    const int dbase = (int)(((long long)r * n + NRNG - 1) / NRNG);
    const int dnext = (int)(((long long)(r + 1) * n + NRNG - 1) / NRNG);
    const int span = dnext - dbase;
    int ebase = 0;
    for (int i = 0; i < r; ++i) ebase += rcur[seg * NRNG + i];

    __shared__ int hist[HSPAN];
    __shared__ int wsum[16];
    const int tid = threadIdx.x, lane = tid & 63, wid = tid >> 6;

    for (int i = tid; i < span; i += 1024) hist[i] = 0;
    __syncthreads();
    for (int i = tid; i < cnt; i += 1024)
        atomicAdd(&hist[(int)(s[i].x & 0xFFFFu) - dbase], 1);
    __syncthreads();
    const int C = (span + 1023) >> 10;
    int v[4];
    int run = 0;
    const int b0 = tid * C;
#pragma unroll 4
    for (int j = 0; j < C; ++j) {
        const int i = b0 + j;
        const int x = (i < span) ? hist[i] : 0;
        v[j] = run;
        run += x;
    }
    int x = run;
#pragma unroll
    for (int o = 1; o < 64; o <<= 1) {
        const int y = __shfl_up(x, o);
        if (lane >= o) x += y;
    }
    if (lane == 63) wsum[wid] = x;
    __syncthreads();
    int wbase = 0;
    for (int i = 0; i < wid; ++i) wbase += wsum[i];
    const int tb = ebase + wbase + (x - run);
#pragma unroll 4
    for (int j = 0; j < C; ++j) {
        const int i = b0 + j;
        if (i < span) hist[i] = tb + v[j];
    }
    __syncthreads();
    for (int i = tid; i < span; i += 1024) off[dbase + i] = hist[i];
    if (r == NRNG - 1 && tid == 0) off[n] = ebase + cnt;
    __syncthreads();
    for (int i = tid; i < cnt; i += 1024) {
        const uint2 e = s[i];
        const int d = (int)(e.x & 0xFFFFu);
        const int p = atomicAdd(&hist[d - dbase], 1);
        const float wf = __uint_as_float(e.y);
        const __half hh = __float2half(wf);
        edg[p] = (e.x >> 16) | ((unsigned int)__half_as_ushort(hh) << 16);
    }
}

// ---------------- edge aggregation v6: fp16 K/Q + fdot2, 4-edge ILP ----------------
__global__ __launch_bounds__(256) void edge_agg3(
    const int* __restrict__ off0, const unsigned int* __restrict__ edg0,
    const unsigned short* __restrict__ K0e, const unsigned short* __restrict__ Q0e,
    const unsigned short* __restrict__ V0e, unsigned short* __restrict__ out0, int nd0,
    const int* __restrict__ off1, const unsigned int* __restrict__ edg1,
    const unsigned short* __restrict__ K1e, const unsigned short* __restrict__ Q1e,
    const unsigned short* __restrict__ V1e, unsigned short* __restrict__ out1, int nd1,
    const int* __restrict__ off2, const unsigned int* __restrict__ edg2,
    const unsigned short* __restrict__ K2e, const unsigned short* __restrict__ Q2e,
    const unsigned short* __restrict__ V2e, unsigned short* __restrict__ out2, int nd2)
{
    const int seg = blockIdx.y;
    const int* off = seg == 0 ? off0 : (seg == 1 ? off1 : off2);
    const unsigned int* edg = seg == 0 ? edg0 : (seg == 1 ? edg1 : edg2);
    const unsigned short* K = seg == 0 ? K0e : (seg == 1 ? K1e : K2e);
    const unsigned short* Q = seg == 0 ? Q0e : (seg == 1 ? Q1e : Q2e);
    const unsigned short* V = seg == 0 ? V0e : (seg == 1 ? V1e : V2e);
    unsigned short* aggb = seg == 0 ? out0 : (seg == 1 ? out1 : out2);
    const int n_dst = seg == 0 ? nd0 : (seg == 1 ? nd1 : nd2);

    const int wv = (blockIdx.x * blockDim.x + threadIdx.x) >> 6;
    const int lane = threadIdx.x & 63;
    const int half = lane >> 5, l5 = lane & 31;
    const int dst = 2 * wv + half;
    const bool valid = dst < n_dst;
    int beg = 0, len = 0;
    if (valid) { beg = off[dst]; len = off[dst + 1] - beg; }
    const int maxLen = max(len, __shfl_xor(len, 32));
    if (maxLen == 0) {
        if (valid) *(ushort4*)(aggb + (size_t)dst * NDIM + 4 * l5) = (ushort4){0, 0, 0, 0};
        return;
    }
    U4h q;
    q.u = make_ushort4(0, 0, 0, 0);
    if (valid) q.u = *(const ushort4*)(Q + (size_t)dst * NDIM + 4 * l5);
    const half2v q01 = q.h.a, q23 = q.h.b;

    float zz[4] = {0.f, 0.f, 0.f, 0.f};
    float a0[4] = {0.f, 0.f, 0.f, 0.f};
    float a1[4] = {0.f, 0.f, 0.f, 0.f};
    float a2[4] = {0.f, 0.f, 0.f, 0.f};
    float a3[4] = {0.f, 0.f, 0.f, 0.f};

    unsigned int ec = (l5 < len) ? edg[beg + l5] : 0u;
    for (int t0 = 0; t0 < maxLen; t0 += 32) {
        unsigned int en = 0u;
        const int t0n = t0 + 32;
        if (t0n < maxLen && t0n + l5 < len) en = edg[beg + t0n + l5];
        const int lim = min(32, maxLen - t0);
        for (int u = 0; u < lim; u += 4) {
            const int sl = (half << 5) + u;
            unsigned int vv[4];
            bool act[4];
            int si[4];
            float wi[4];
#pragma unroll
            for (int k = 0; k < 4; ++k) {
                vv[k] = (unsigned int)__shfl((int)ec, sl + k);
                act[k] = (u + k < lim) && ((t0 + u + k) < len);
                si[k] = (int)(vv[k] & 0xFFFFu);
                wi[k] = __half2float(__ushort_as_half((unsigned short)(vv[k] >> 16)));
            }
            U4h ku[4];
            ushort4 vr[4];
#pragma unroll
            for (int k = 0; k < 4; ++k) {
                ku[k].u = *(const ushort4*)(K + (size_t)si[k] * NDIM + 4 * l5);
                vr[k] = *(const ushort4*)(V + (size_t)si[k] * NDIM + 4 * l5);
            }
            float d[4];
#pragma unroll
            for (int k = 0; k < 4; ++k) {
#if __has_builtin(__builtin_amdgcn_fdot2)
                float dd = __builtin_amdgcn_fdot2(ku[k].h.a, q01, 0.f, false);
                d[k] = __builtin_amdgcn_fdot2(ku[k].h.b, q23, dd, false);
#else
                d[k] = (float)ku[k].h.a[0] * (float)q01[0] + (float)ku[k].h.a[1] * (float)q01[1]
                     + (float)ku[k].h.b[0] * (float)q23[0] + (float)ku[k].h.b[1] * (float)q23[1];
#endif
            }
#pragma unroll
            for (int k = 0; k < 4; ++k) d[k] += __shfl_xor(d[k], 1);
#pragma unroll
            for (int k = 0; k < 4; ++k) d[k] += __shfl_xor(d[k], 2);
#pragma unroll
            for (int k = 0; k < 4; ++k) {
                const float p = act[k] ? exp2f(d[k] * wi[k]) : 0.f;
                zz[k] += p;
                a0[k] += p * bf2f(vr[k].x);
                a1[k] += p * bf2f(vr[k].y);
                a2[k] += p * bf2f(vr[k].z);
                a3[k] += p * bf2f(vr[k].w);
            }
        }
        ec = en;
    }
    if (valid) {
        const float z = (zz[0] + zz[1]) + (zz[2] + zz[3]);
        const float inv = (len > 0) ? 1.f / z : 0.f;
        ushort4 o;
        o.x = f2bf(((a0[0] + a0[1]) + (a0[2] + a0[3])) * inv);
        o.y = f2bf(((a1[0] + a1[1]) + (a1[2] + a1[3])) * inv);
        o.z = f2bf(((a2[0] + a2[1]) + (a2[2] + a2[3])) * inv);
        o.w = f2bf(((a3[0] + a3[1]) + (a3[2] + a3[3])) * inv);
        *(ushort4*)(aggb + (size_t)dst * NDIM + 4 * l5) = o;
    }
}

extern "C" void kernel_launch(void* const* d_in, const int* in_sizes, int n_in,
                              void* d_out, int out_size, void* d_ws, size_t ws_size,
                              hipStream_t stream)
{
    const float* feat0 = (const float*)d_in[0];
    const float* feat1 = (const float*)d_in[1];
    const float* ev0 = (const float*)d_in[2];
    const float* ev1 = (const float*)d_in[3];
    const float* ev2 = (const float*)d_in[4];
    const int* src0 = (const int*)d_in[5];
    const int* dst0 = (const int*)d_in[6];
    const int* src1 = (const int*)d_in[7];
    const int* dst1 = (const int*)d_in[8];
    const int* src2 = (const int*)d_in[9];
    const int* dst2 = (const int*)d_in[10];
    const float* Kw = (const float*)d_in[11];
    const float* Kb = (const float*)d_in[12];
    const float* Qw = (const float*)d_in[13];
    const float* Qb = (const float*)d_in[14];
    const float* Vw = (const float*)d_in[15];
    const float* Vb = (const float*)d_in[16];
    const float* Aw = (const float*)d_in[17];
    const float* Ab = (const float*)d_in[18];
    const float* ew = (const float*)d_in[19];
    const float* eb = (const float*)d_in[20];
    const float* skip = (const float*)d_in[21];

    const int n0 = in_sizes[0] / NDIM;
    const int n1 = in_sizes[1] / NDIM;
    const int E0 = in_sizes[5];
    const int E1 = in_sizes[7];
    const int E2 = in_sizes[9];
    if (max(n0, n1) > 65504) return;
    const int Emax = max(E0, max(E1, E2));
    const int cap = Emax / NRNG + 8192;

    auto rup = [](size_t b) { return (b + 255) & ~size_t(255); };
    const size_t need =
        rup((size_t)8 * 16384 * 2) +
        rup((size_t)n0 * NDIM * 2) * 3 +
        rup((size_t)n1 * NDIM * 2) * 3 +
        rup((size_t)n1 * NDIM * 2) +
        rup((size_t)n0 * NDIM * 2) * 2 +
        rup((size_t)(n1 + 1) * 4) +
        rup((size_t)(n0 + 1) * 4) * 2 +
        rup((size_t)128 * 4) +
        rup((size_t)3 * UNITS * NRNG * 4) +
        rup((size_t)3 * NRNG * cap * 8) +
        rup((size_t)E0 * 4) + rup((size_t)E1 * 4) + rup((size_t)E2 * 4);
    if (ws_size < need) return;

    char* p = (char*)d_ws;
    auto alloc = [&](size_t bytes) -> char* {
        char* r = p;
        p += (bytes + 255) & ~size_t(255);
        return r;
    };
    unsigned short* Wtbuf = (unsigned short*)alloc((size_t)8 * 16384 * 2);
    unsigned short* K0 = (unsigned short*)alloc((size_t)n0 * NDIM * 2);
    unsigned short* Q0 = (unsigned short*)alloc((size_t)n0 * NDIM * 2);
    unsigned short* V0 = (unsigned short*)alloc((size_t)n0 * NDIM * 2);
    unsigned short* K1 = (unsigned short*)alloc((size_t)n1 * NDIM * 2);
    unsigned short* Q1 = (unsigned short*)alloc((size_t)n1 * NDIM * 2);
    unsigned short* V1 = (unsigned short*)alloc((size_t)n1 * NDIM * 2);
    unsigned short* aggb1  = (unsigned short*)alloc((size_t)n1 * NDIM * 2);
    unsigned short* aggb0a = (unsigned short*)alloc((size_t)n0 * NDIM * 2);
    unsigned short* aggb0b = (unsigned short*)alloc((size_t)n0 * NDIM * 2);
    int* off0 = (int*)alloc((size_t)(n1 + 1) * 4);
    int* off1 = (int*)alloc((size_t)(n0 + 1) * 4);
    int* off2 = (int*)alloc((size_t)(n0 + 1) * 4);
    int* rcur = (int*)alloc((size_t)128 * 4);
    int* cnts = (int*)alloc((size_t)3 * UNITS * NRNG * 4);
    uint2* stg = (uint2*)alloc((size_t)3 * NRNG * cap * 8);
    unsigned int* edg0 = (unsigned int*)alloc((size_t)E0 * 4);
    unsigned int* edg1 = (unsigned int*)alloc((size_t)E1 * 4);
    unsigned int* edg2 = (unsigned int*)alloc((size_t)E2 * 4);

    dim3 blk(256);
    const int blocks0 = (n0 + 63) / 64, blocks1 = (n1 + 63) / 64;

    wt_prep<<<8, 256, 0, stream>>>(Kw, Qw, Vw, Aw, Wtbuf);
    gemm_kqv<<<blocks0 + blocks1, blk, 0, stream>>>(feat0, feat1, Wtbuf, Kb, Qb, Vb,
                                                    K0, Q0, V0, K1, Q1, V1, n0, n1, blocks0);

    bucket_count<<<dim3(NBK, 3), blk, 0, stream>>>(dst0, E0, dst1, E1, dst2, E2, n0, n1, cnts);
    bucket_scan<<<3 * NRNG, blk, 0, stream>>>(cnts, rcur);
    bucket_write<<<dim3(NBK, 3), blk, 0, stream>>>(dst0, src0, ev0, E0,
                                                   dst1, src1, ev1, E1,
                                                   dst2, src2, ev2, E2,
                                                   n0, n1, ew, eb, cnts, stg, cap);
    sortB<<<dim3(NRNG, 3), 1024, 0, stream>>>(stg, cap, rcur,
                                              n1, off0, edg0,
                                              n0, off1, edg1,
                                              n0, off2, edg2);

    const int nmax = (n0 > n1) ? n0 : n1;
    const int ebx = ((nmax + 1) / 2 + 3) / 4;
    edge_agg3<<<dim3(ebx, 3), blk, 0, stream>>>(
        off0, edg0, K0, Q1, V0, aggb1, n1,
        off1, edg1, K1, Q0, V1, aggb0a, n0,
        off2, edg2, K0, Q0, V0, aggb0b, n0);

    gemm_out<<<blocks0 + blocks1, blk, 0, stream>>>(aggb0a, aggb0b, aggb1, Wtbuf, Ab,
                                                    feat0, feat1, skip, (float*)d_out,
                                                    n0, n1, blocks0);
}

// Round 21
// 395.937 us; speedup vs baseline: 1.0141x; 1.0141x over previous
//
#include <hip/hip_runtime.h>
#include <hip/hip_bf16.h>
#include <hip/hip_fp16.h>
#include <math.h>

// HEAT layer. Round 21: revert r19/r20 experiments (4-edge ILP cost occupancy
// 76->68% at the fetch floor; half-width epilogue null). Exact round-18 anchor
// (396us): wt_prep / gemm_kqv / bucket CSR / sortB / edge_agg3(2-edge) / gemm_out.

#define NDIM 128
#define NRNG 32
#define NBK 512
#define UNITS (NBK * 4)
#define HSPAN 2048

typedef __attribute__((ext_vector_type(8))) short short8;
typedef __attribute__((ext_vector_type(4))) float f32x4;
typedef __attribute__((ext_vector_type(2))) _Float16 half2v;

__device__ __forceinline__ float bf2f(unsigned short u) {
    union { unsigned int i; float f; } x; x.i = ((unsigned int)u) << 16; return x.f;
}
__device__ __forceinline__ unsigned short f2bf(float f) {
    unsigned int u = __float_as_uint(f);
    unsigned int r = (u + 0x7FFFu + ((u >> 16) & 1u)) >> 16;   // RNE
    return (unsigned short)r;
}
__device__ __forceinline__ int range_of(int d, int n) {
    return (int)(((long long)d * NRNG) / n);
}
union U4h { ushort4 u; struct { half2v a, b; } h; };

// ---------------- weight prep: 8 mats f32[k][n] -> bf16 [n][k], LDS transpose ----------------
__global__ __launch_bounds__(256) void wt_prep(const float* __restrict__ Kw, const float* __restrict__ Qw,
                                               const float* __restrict__ Vw, const float* __restrict__ Aw,
                                               unsigned short* __restrict__ Wtbuf)
{
    const int b = blockIdx.x;        // t*4 + m
    const int t = b >> 2, m = b & 3;
    const float* src = (m == 0 ? Kw : m == 1 ? Qw : m == 2 ? Vw : Aw) + (size_t)t * 16384;
    unsigned short* dst = Wtbuf + (size_t)b * 16384;
    const int tid = threadIdx.x;
    __shared__ float tile[64][132];
#pragma unroll
    for (int h = 0; h < 2; ++h) {
        const int k0 = h * 64;
        for (int idx = tid; idx < 64 * 32; idx += 256) {
            const int kr = idx >> 5;
            const int c4 = (idx & 31) * 4;
            const float4 v = *(const float4*)(src + (size_t)(k0 + kr) * 128 + c4);
            tile[kr][c4 + 0] = v.x; tile[kr][c4 + 1] = v.y;
            tile[kr][c4 + 2] = v.z; tile[kr][c4 + 3] = v.w;
        }
        __syncthreads();
        for (int idx = tid; idx < 128 * 16; idx += 256) {
            const int nn = idx >> 4;
            const int kk4 = (idx & 15) * 4;
            ushort4 o;
            o.x = f2bf(tile[kk4 + 0][nn]); o.y = f2bf(tile[kk4 + 1][nn]);
            o.z = f2bf(tile[kk4 + 2][nn]); o.w = f2bf(tile[kk4 + 3][nn]);
            *(ushort4*)(dst + (size_t)nn * 128 + k0 + kk4) = o;
        }
        __syncthreads();
    }
}

// ---------------- fused K/Q/V MFMA GEMM (K,Q out fp16; V out bf16) ----------------
__global__ __launch_bounds__(256) void gemm_kqv(
    const float* __restrict__ feat0, const float* __restrict__ feat1,
    const unsigned short* __restrict__ Wtbuf,
    const float* __restrict__ Kb, const float* __restrict__ Qb, const float* __restrict__ Vb,
    unsigned short* __restrict__ K0o, unsigned short* __restrict__ Q0o, unsigned short* __restrict__ V0o,
    unsigned short* __restrict__ K1o, unsigned short* __restrict__ Q1o, unsigned short* __restrict__ V1o,
    int n0, int n1, int blocks0)
{
    const int b = blockIdx.x;
    const bool t1 = (b >= blocks0);
    const float* feat = t1 ? feat1 : feat0;
    const int n = t1 ? n1 : n0;
    const int boff = t1 ? NDIM : 0;
    const unsigned short* Wt = Wtbuf + (t1 ? 4 * 16384 : 0);
    unsigned short* outs[3];
    outs[0] = t1 ? K1o : K0o; outs[1] = t1 ? Q1o : Q0o; outs[2] = t1 ? V1o : V0o;
    const float* biases[3] = {Kb + boff, Qb + boff, Vb + boff};

    const int tid = threadIdx.x;
    const int w = tid >> 6, lane = tid & 63;
    const int r16 = lane & 15, kg = lane >> 4;
    const int brow = (t1 ? b - blocks0 : b) * 64;
    const int arow = min(brow + w * 16 + r16, n - 1);

    __shared__ float sacc[64][129];

    short8 afr[4];
#pragma unroll
    for (int k0i = 0; k0i < 4; ++k0i) {
        const float* ap = feat + (size_t)arow * NDIM + k0i * 32 + kg * 8;
        const float4 lo = *(const float4*)ap;
        const float4 hi = *(const float4*)(ap + 4);
        short8 a;
        a[0] = (short)f2bf(lo.x); a[1] = (short)f2bf(lo.y);
        a[2] = (short)f2bf(lo.z); a[3] = (short)f2bf(lo.w);
        a[4] = (short)f2bf(hi.x); a[5] = (short)f2bf(hi.y);
        a[6] = (short)f2bf(hi.z); a[7] = (short)f2bf(hi.w);
        afr[k0i] = a;
    }
    const int c8 = (lane & 15) * 8;
#pragma unroll
    for (int m = 0; m < 3; ++m) {
        const unsigned short* wt = Wt + (size_t)m * 16384;
        f32x4 acc[8];
#pragma unroll
        for (int c = 0; c < 8; ++c) acc[c] = (f32x4){0.f, 0.f, 0.f, 0.f};
#pragma unroll
        for (int k0i = 0; k0i < 4; ++k0i)
#pragma unroll
            for (int c = 0; c < 8; ++c) {
                const short8 bb = *(const short8*)(wt + (size_t)(16 * c + r16) * NDIM + k0i * 32 + kg * 8);
                acc[c] = __builtin_amdgcn_mfma_f32_16x16x32_bf16(afr[k0i], bb, acc[c], 0, 0, 0);
            }
        __syncthreads();
#pragma unroll
        for (int c = 0; c < 8; ++c)
#pragma unroll
            for (int j = 0; j < 4; ++j)
                sacc[w * 16 + kg * 4 + j][16 * c + r16] = acc[c][j];
        __syncthreads();
        const float4 blo = *(const float4*)(biases[m] + c8);
        const float4 bhi = *(const float4*)(biases[m] + c8 + 4);
        const float bias8[8] = {blo.x, blo.y, blo.z, blo.w, bhi.x, bhi.y, bhi.z, bhi.w};
#pragma unroll
        for (int j = 0; j < 4; ++j) {
            const int rloc = w * 16 + (lane >> 4) + j * 4;
            const int grow = brow + rloc;
            if (grow < n) {
                short8 o;
#pragma unroll
                for (int i = 0; i < 8; ++i) {
                    const float x = sacc[rloc][c8 + i] + bias8[i];
                    o[i] = (m < 2) ? (short)__half_as_ushort(__float2half(x))  // K,Q -> fp16
                                   : (short)f2bf(x);                           // V   -> bf16
                }
                *(short8*)(outs[m] + (size_t)grow * NDIM + c8) = o;
            }
        }
    }
}

// ---------------- fused output MFMA GEMM, LDS-staged epilogue ----------------
__global__ __launch_bounds__(256) void gemm_out(
    const unsigned short* __restrict__ aggb0a, const unsigned short* __restrict__ aggb0b,
    const unsigned short* __restrict__ aggb1,
    const unsigned short* __restrict__ Wtbuf, const float* __restrict__ Ab,
    const float* __restrict__ feat0, const float* __restrict__ feat1,
    const float* __restrict__ skip, float* __restrict__ out,
    int n0, int n1, int blocks0)
{
    const int b = blockIdx.x;
    const bool t1 = (b >= blocks0);
    const int n = t1 ? n1 : n0;
    const unsigned short* A1 = t1 ? aggb1 : aggb0a;
    const unsigned short* A2 = t1 ? (const unsigned short*)nullptr : aggb0b;
    const unsigned short* Wt = Wtbuf + (t1 ? 7 : 3) * 16384;
    const float* bias = Ab + (t1 ? NDIM : 0);
    const float* feat = t1 ? feat1 : feat0;
    float* C = out + (t1 ? (size_t)n0 * NDIM : 0);
    const int nid = t1 ? 1 : 0;

    const int tid = threadIdx.x;
    const int w = tid >> 6, lane = tid & 63;
    const int r16 = lane & 15, kg = lane >> 4;
    const int brow = (t1 ? b - blocks0 : b) * 64;
    const int arow = min(brow + w * 16 + r16, n - 1);

    __shared__ float sacc[64][129];

    short8 afr[4];
#pragma unroll
    for (int k0i = 0; k0i < 4; ++k0i) {
        short8 a = *(const short8*)(A1 + (size_t)arow * NDIM + k0i * 32 + kg * 8);
        if (!t1) {
            const short8 bb = *(const short8*)(A2 + (size_t)arow * NDIM + k0i * 32 + kg * 8);
#pragma unroll
            for (int j = 0; j < 8; ++j) {
                const float v = 0.5f * (bf2f((unsigned short)a[j]) + bf2f((unsigned short)bb[j]));
                a[j] = (short)f2bf(v);
            }
        }
        afr[k0i] = a;
    }
    f32x4 acc[8];
#pragma unroll
    for (int c = 0; c < 8; ++c) acc[c] = (f32x4){0.f, 0.f, 0.f, 0.f};
#pragma unroll
    for (int k0i = 0; k0i < 4; ++k0i)
#pragma unroll
        for (int c = 0; c < 8; ++c) {
            const short8 bb = *(const short8*)(Wt + (size_t)(16 * c + r16) * NDIM + k0i * 32 + kg * 8);
            acc[c] = __builtin_amdgcn_mfma_f32_16x16x32_bf16(afr[k0i], bb, acc[c], 0, 0, 0);
        }
    __syncthreads();
#pragma unroll
    for (int c = 0; c < 8; ++c)
#pragma unroll
        for (int j = 0; j < 4; ++j)
            sacc[w * 16 + kg * 4 + j][16 * c + r16] = acc[c][j];
    __syncthreads();

    const float sk = skip[nid];
    const float alpha = 1.f / (1.f + __expf(-sk));
    const float beta = 1.f - alpha;
    const int c8 = (lane & 15) * 8;
    const float4 blo = *(const float4*)(bias + c8);
    const float4 bhi = *(const float4*)(bias + c8 + 4);
#pragma unroll
    for (int j = 0; j < 4; ++j) {
        const int rloc = w * 16 + (lane >> 4) + j * 4;
        const int grow = brow + rloc;
        if (grow < n) {
            const float4 fa = *(const float4*)(feat + (size_t)grow * NDIM + c8);
            const float4 fb = *(const float4*)(feat + (size_t)grow * NDIM + c8 + 4);
            float4 oa, ob;
            oa.x = (sacc[rloc][c8 + 0] + blo.x) * alpha + fa.x * beta;
            oa.y = (sacc[rloc][c8 + 1] + blo.y) * alpha + fa.y * beta;
            oa.z = (sacc[rloc][c8 + 2] + blo.z) * alpha + fa.z * beta;
            oa.w = (sacc[rloc][c8 + 3] + blo.w) * alpha + fa.w * beta;
            ob.x = (sacc[rloc][c8 + 4] + bhi.x) * alpha + fb.x * beta;
            ob.y = (sacc[rloc][c8 + 5] + bhi.y) * alpha + fb.y * beta;
            ob.z = (sacc[rloc][c8 + 6] + bhi.z) * alpha + fb.z * beta;
            ob.w = (sacc[rloc][c8 + 7] + bhi.w) * alpha + fb.w * beta;
            *(float4*)(C + (size_t)grow * NDIM + c8) = oa;
            *(float4*)(C + (size_t)grow * NDIM + c8 + 4) = ob;
        }
    }
}

// ---------------- phase A1: per-unit range counts ----------------
__global__ __launch_bounds__(256) void bucket_count(
    const int* __restrict__ d0, int E0, const int* __restrict__ d1, int E1,
    const int* __restrict__ d2, int E2, int n0, int n1, int* __restrict__ cnts)
{
    const int seg = blockIdx.y;
    const int* dst = seg == 0 ? d0 : (seg == 1 ? d1 : d2);
    const int E = seg == 0 ? E0 : (seg == 1 ? E1 : E2);
    const int ns = seg == 0 ? n1 : n0;
    const int unit = blockIdx.x * 4 + (threadIdx.x >> 6);
    const int lane = threadIdx.x & 63;
    const int span = (E + UNITS - 1) / UNITS;
    const int b = unit * span;
    const int e = min(b + span, E);

    int run[NRNG];
#pragma unroll
    for (int r0 = 0; r0 < NRNG; ++r0) run[r0] = 0;
    for (int i0 = b; i0 < e; i0 += 64) {
        const int i = i0 + lane;
        const bool v = i < e;
        const int d = v ? dst[i] : 0;
        const unsigned int r = v ? (unsigned int)range_of(d, ns) : 0xFFu;
#pragma unroll
        for (int r0 = 0; r0 < NRNG; ++r0)
            run[r0] += __popcll(__ballot(r == (unsigned int)r0));
    }
    if (lane == 0) {
        int* c = cnts + ((size_t)seg * UNITS + unit) * NRNG;
#pragma unroll
        for (int r0 = 0; r0 < NRNG; ++r0) c[r0] = run[r0];
    }
}

// ---------------- phase A2: exclusive scan of unit counts; totals -> rcur ----------------
__global__ __launch_bounds__(256) void bucket_scan(int* __restrict__ cnts, int* __restrict__ rcur)
{
    const int seg = blockIdx.x >> 5;
    const int r = blockIdx.x & 31;
    const int t = threadIdx.x, lane = t & 63, w = t >> 6;

    int v[8];
    int run = 0;
#pragma unroll
    for (int j = 0; j < 8; ++j) {
        const int u = t * 8 + j;
        const int x = cnts[((size_t)seg * UNITS + u) * NRNG + r];
        v[j] = run;
        run += x;
    }
    const int tsum = run;
    int x = tsum;
#pragma unroll
    for (int o = 1; o < 64; o <<= 1) {
        const int y = __shfl_up(x, o);
        if (lane >= o) x += y;
    }
    const int wexc = x - tsum;
    __shared__ int wsum[4];
    if (lane == 63) wsum[w] = x;
    __syncthreads();
    int wbase = 0;
    for (int i = 0; i < w; ++i) wbase += wsum[i];
    const int base = wbase + wexc;
#pragma unroll
    for (int j = 0; j < 8; ++j) {
        const int u = t * 8 + j;
        cnts[((size_t)seg * UNITS + u) * NRNG + r] = base + v[j];
    }
    if (t == 255) rcur[seg * NRNG + r] = base + tsum;
}

// ---------------- phase A3: deterministic staged write ----------------
__global__ __launch_bounds__(256) void bucket_write(
    const int* __restrict__ d0, const int* __restrict__ s0, const float* __restrict__ e0, int E0,
    const int* __restrict__ d1, const int* __restrict__ s1, const float* __restrict__ e1, int E1,
    const int* __restrict__ d2, const int* __restrict__ s2, const float* __restrict__ e2, int E2,
    int n0, int n1, const float* __restrict__ ew, const float* __restrict__ eb,
    const int* __restrict__ cnts, uint2* __restrict__ stg, int cap)
{
    const int seg = blockIdx.y;
    const int* dst = seg == 0 ? d0 : (seg == 1 ? d1 : d2);
    const int* src = seg == 0 ? s0 : (seg == 1 ? s1 : s2);
    const float* ev = seg == 0 ? e0 : (seg == 1 ? e1 : e2);
    const int E = seg == 0 ? E0 : (seg == 1 ? E1 : E2);
    const int ns = seg == 0 ? n1 : n0;
    const int unit = blockIdx.x * 4 + (threadIdx.x >> 6);
    const int lane = threadIdx.x & 63;
    const int span = (E + UNITS - 1) / UNITS;
    const int b = unit * span;
    const int e = min(b + span, E);
    const float LOG2E = 1.4426950408889634f;
    const float ews = ew[0] * 0.25f * LOG2E;
    const float ebs = eb[0] * 0.25f * LOG2E;
    uint2* sbase = stg + (size_t)seg * NRNG * cap;

    int run[NRNG];
    {
        const int* c = cnts + ((size_t)seg * UNITS + unit) * NRNG;
#pragma unroll
        for (int r0 = 0; r0 < NRNG; ++r0) run[r0] = c[r0];
    }
    for (int i0 = b; i0 < e; i0 += 64) {
        const int i = i0 + lane;
        const bool v = i < e;
        int d = 0, s = 0; float ee = 0.f;
        if (v) { d = dst[i]; s = src[i]; ee = ev[i]; }
        const unsigned int r = v ? (unsigned int)range_of(d, ns) : 0xFFu;
#pragma unroll
        for (int r0 = 0; r0 < NRNG; ++r0) {
            const unsigned long long m = __ballot(r == (unsigned int)r0);
            if (m == 0ull) continue;
            if (r == (unsigned int)r0) {
                const int off = run[r0] + __popcll(m & ((1ull << lane) - 1ull));
                sbase[(size_t)r0 * cap + off] =
                    make_uint2((unsigned int)d | ((unsigned int)s << 16), __float_as_uint(ee * ews + ebs));
            }
            run[r0] += __popcll(m);
        }
    }
}

// ---------------- phase B: per-range LDS counting sort -> off[] + edg[] (u32) ----------------
__global__ __launch_bounds__(1024) void sortB(
    const uint2* __restrict__ stg, int cap, const int* __restrict__ rcur,
    int nA, int* __restrict__ offA, unsigned int* __restrict__ gA,
    int nB, int* __restrict__ offB, unsigned int* __restrict__ gB,
    int nC, int* __restrict__ offC, unsigned int* __restrict__ gC)
{
    const int seg = blockIdx.y;
    const int r = blockIdx.x;
    const int n = seg == 0 ? nA : (seg == 1 ? nB : nC);
    int* off = seg == 0 ? offA : (seg == 1 ? offB : offC);
    unsigned int* edg = seg == 0 ? gA : (seg == 1 ? gB : gC);
    const int cnt = rcur[seg * NRNG + r];
    const uint2* s = stg + ((size_t)seg * NRNG + r) * cap;
    const int dbase = (int)(((long long)r * n + NRNG - 1) / NRNG);
    const int dnext = (int)(((long long)(r + 1) * n + NRNG - 1) / NRNG);
    const int span = dnext - dbase;
    int ebase = 0;
    for (int i = 0; i < r; ++i) ebase += rcur[seg * NRNG + i];

    __shared__ int hist[HSPAN];
    __shared__ int wsum[16];
    const int tid = threadIdx.x, lane = tid & 63, wid = tid >> 6;

    for (int i = tid; i < span; i += 1024) hist[i] = 0;
    __syncthreads();
    for (int i = tid; i < cnt; i += 1024)
        atomicAdd(&hist[(int)(s[i].x & 0xFFFFu) - dbase], 1);
    __syncthreads();
    const int C = (span + 1023) >> 10;
    int v[4];
    int run = 0;
    const int b0 = tid * C;
#pragma unroll 4
    for (int j = 0; j < C; ++j) {
        const int i = b0 + j;
        const int x = (i < span) ? hist[i] : 0;
        v[j] = run;
        run += x;
    }
    int x = run;
#pragma unroll
    for (int o = 1; o < 64; o <<= 1) {
        const int y = __shfl_up(x, o);
        if (lane >= o) x += y;
    }
    if (lane == 63) wsum[wid] = x;
    __syncthreads();
    int wbase = 0;
    for (int i = 0; i < wid; ++i) wbase += wsum[i];
    const int tb = ebase + wbase + (x - run);
#pragma unroll 4
    for (int j = 0; j < C; ++j) {
        const int i = b0 + j;
        if (i < span) hist[i] = tb + v[j];
    }
    __syncthreads();
    for (int i = tid; i < span; i += 1024) off[dbase + i] = hist[i];
    if (r == NRNG - 1 && tid == 0) off[n] = ebase + cnt;
    __syncthreads();
    for (int i = tid; i < cnt; i += 1024) {
        const uint2 e = s[i];
        const int d = (int)(e.x & 0xFFFFu);
        const int p = atomicAdd(&hist[d - dbase], 1);
        const float wf = __uint_as_float(e.y);
        const __half hh = __float2half(wf);
        edg[p] = (e.x >> 16) | ((unsigned int)__half_as_ushort(hh) << 16);
    }
}

// ---------------- edge aggregation v5: fp16 K/Q + fdot2, 2-edge ILP ----------------
__global__ __launch_bounds__(256) void edge_agg3(
    const int* __restrict__ off0, const unsigned int* __restrict__ edg0,
    const unsigned short* __restrict__ K0e, const unsigned short* __restrict__ Q0e,
    const unsigned short* __restrict__ V0e, unsigned short* __restrict__ out0, int nd0,
    const int* __restrict__ off1, const unsigned int* __restrict__ edg1,
    const unsigned short* __restrict__ K1e, const unsigned short* __restrict__ Q1e,
    const unsigned short* __restrict__ V1e, unsigned short* __restrict__ out1, int nd1,
    const int* __restrict__ off2, const unsigned int* __restrict__ edg2,
    const unsigned short* __restrict__ K2e, const unsigned short* __restrict__ Q2e,
    const unsigned short* __restrict__ V2e, unsigned short* __restrict__ out2, int nd2)
{
    const int seg = blockIdx.y;
    const int* off = seg == 0 ? off0 : (seg == 1 ? off1 : off2);
    const unsigned int* edg = seg == 0 ? edg0 : (seg == 1 ? edg1 : edg2);
    const unsigned short* K = seg == 0 ? K0e : (seg == 1 ? K1e : K2e);
    const unsigned short* Q = seg == 0 ? Q0e : (seg == 1 ? Q1e : Q2e);
    const unsigned short* V = seg == 0 ? V0e : (seg == 1 ? V1e : V2e);
    unsigned short* aggb = seg == 0 ? out0 : (seg == 1 ? out1 : out2);
    const int n_dst = seg == 0 ? nd0 : (seg == 1 ? nd1 : nd2);

    const int wv = (blockIdx.x * blockDim.x + threadIdx.x) >> 6;
    const int lane = threadIdx.x & 63;
    const int half = lane >> 5, l5 = lane & 31;
    const int dst = 2 * wv + half;
    const bool valid = dst < n_dst;
    int beg = 0, len = 0;
    if (valid) { beg = off[dst]; len = off[dst + 1] - beg; }
    const int maxLen = max(len, __shfl_xor(len, 32));
    if (maxLen == 0) {
        if (valid) *(ushort4*)(aggb + (size_t)dst * NDIM + 4 * l5) = (ushort4){0, 0, 0, 0};
        return;
    }
    U4h q;
    q.u = make_ushort4(0, 0, 0, 0);
    if (valid) q.u = *(const ushort4*)(Q + (size_t)dst * NDIM + 4 * l5);
    const half2v q01 = q.h.a, q23 = q.h.b;

    float zA = 0.f, aA0 = 0.f, aA1 = 0.f, aA2 = 0.f, aA3 = 0.f;
    float zB = 0.f, aB0 = 0.f, aB1 = 0.f, aB2 = 0.f, aB3 = 0.f;

    unsigned int ec = (l5 < len) ? edg[beg + l5] : 0u;
    for (int t0 = 0; t0 < maxLen; t0 += 32) {
        unsigned int en = 0u;
        const int t0n = t0 + 32;
        if (t0n < maxLen && t0n + l5 < len) en = edg[beg + t0n + l5];
        const int lim = min(32, maxLen - t0);
        for (int u = 0; u < lim; u += 2) {
            const int sl0 = (half << 5) + u;
            const unsigned int v0 = (unsigned int)__shfl((int)ec, sl0);
            const unsigned int v1 = (unsigned int)__shfl((int)ec, sl0 + 1);
            const bool act0 = (t0 + u) < len;
            const bool act1 = (u + 1 < lim) && ((t0 + u + 1) < len);
            const int s0 = (int)(v0 & 0xFFFFu);
            const int s1 = (int)(v1 & 0xFFFFu);
            const float w0 = __half2float(__ushort_as_half((unsigned short)(v0 >> 16)));
            const float w1 = __half2float(__ushort_as_half((unsigned short)(v1 >> 16)));
            U4h k0u, k1u;
            k0u.u = *(const ushort4*)(K + (size_t)s0 * NDIM + 4 * l5);
            k1u.u = *(const ushort4*)(K + (size_t)s1 * NDIM + 4 * l5);
            const ushort4 vr0 = *(const ushort4*)(V + (size_t)s0 * NDIM + 4 * l5);
            const ushort4 vr1 = *(const ushort4*)(V + (size_t)s1 * NDIM + 4 * l5);
#if __has_builtin(__builtin_amdgcn_fdot2)
            float d0 = __builtin_amdgcn_fdot2(k0u.h.a, q01, 0.f, false);
            d0 = __builtin_amdgcn_fdot2(k0u.h.b, q23, d0, false);
            float d1 = __builtin_amdgcn_fdot2(k1u.h.a, q01, 0.f, false);
            d1 = __builtin_amdgcn_fdot2(k1u.h.b, q23, d1, false);
#else
            float d0 = (float)k0u.h.a[0] * (float)q01[0] + (float)k0u.h.a[1] * (float)q01[1]
                     + (float)k0u.h.b[0] * (float)q23[0] + (float)k0u.h.b[1] * (float)q23[1];
            float d1 = (float)k1u.h.a[0] * (float)q01[0] + (float)k1u.h.a[1] * (float)q01[1]
                     + (float)k1u.h.b[0] * (float)q23[0] + (float)k1u.h.b[1] * (float)q23[1];
#endif
            d0 += __shfl_xor(d0, 1);
            d1 += __shfl_xor(d1, 1);
            d0 += __shfl_xor(d0, 2);
            d1 += __shfl_xor(d1, 2);
            const float p0 = act0 ? exp2f(d0 * w0) : 0.f;
            const float p1 = act1 ? exp2f(d1 * w1) : 0.f;
            zA += p0;
            aA0 += p0 * bf2f(vr0.x); aA1 += p0 * bf2f(vr0.y);
            aA2 += p0 * bf2f(vr0.z); aA3 += p0 * bf2f(vr0.w);
            zB += p1;
            aB0 += p1 * bf2f(vr1.x); aB1 += p1 * bf2f(vr1.y);
            aB2 += p1 * bf2f(vr1.z); aB3 += p1 * bf2f(vr1.w);
        }
        ec = en;
    }
    if (valid) {
        const float z = zA + zB;
        const float inv = (len > 0) ? 1.f / z : 0.f;
        ushort4 o;
        o.x = f2bf((aA0 + aB0) * inv); o.y = f2bf((aA1 + aB1) * inv);
        o.z = f2bf((aA2 + aB2) * inv); o.w = f2bf((aA3 + aB3) * inv);
        *(ushort4*)(aggb + (size_t)dst * NDIM + 4 * l5) = o;
    }
}

extern "C" void kernel_launch(void* const* d_in, const int* in_sizes, int n_in,
                              void* d_out, int out_size, void* d_ws, size_t ws_size,
                              hipStream_t stream)
{
    const float* feat0 = (const float*)d_in[0];
    const float* feat1 = (const float*)d_in[1];
    const float* ev0 = (const float*)d_in[2];
    const float* ev1 = (const float*)d_in[3];
    const float* ev2 = (const float*)d_in[4];
    const int* src0 = (const int*)d_in[5];
    const int* dst0 = (const int*)d_in[6];
    const int* src1 = (const int*)d_in[7];
    const int* dst1 = (const int*)d_in[8];
    const int* src2 = (const int*)d_in[9];
    const int* dst2 = (const int*)d_in[10];
    const float* Kw = (const float*)d_in[11];
    const float* Kb = (const float*)d_in[12];
    const float* Qw = (const float*)d_in[13];
    const float* Qb = (const float*)d_in[14];
    const float* Vw = (const float*)d_in[15];
    const float* Vb = (const float*)d_in[16];
    const float* Aw = (const float*)d_in[17];
    const float* Ab = (const float*)d_in[18];
    const float* ew = (const float*)d_in[19];
    const float* eb = (const float*)d_in[20];
    const float* skip = (const float*)d_in[21];

    const int n0 = in_sizes[0] / NDIM;
    const int n1 = in_sizes[1] / NDIM;
    const int E0 = in_sizes[5];
    const int E1 = in_sizes[7];
    const int E2 = in_sizes[9];
    if (max(n0, n1) > 65504) return;
    const int Emax = max(E0, max(E1, E2));
    const int cap = Emax / NRNG + 8192;

    auto rup = [](size_t b) { return (b + 255) & ~size_t(255); };
    const size_t need =
        rup((size_t)8 * 16384 * 2) +
        rup((size_t)n0 * NDIM * 2) * 3 +
        rup((size_t)n1 * NDIM * 2) * 3 +
        rup((size_t)n1 * NDIM * 2) +
        rup((size_t)n0 * NDIM * 2) * 2 +
        rup((size_t)(n1 + 1) * 4) +
        rup((size_t)(n0 + 1) * 4) * 2 +
        rup((size_t)128 * 4) +
        rup((size_t)3 * UNITS * NRNG * 4) +
        rup((size_t)3 * NRNG * cap * 8) +
        rup((size_t)E0 * 4) + rup((size_t)E1 * 4) + rup((size_t)E2 * 4);
    if (ws_size < need) return;

    char* p = (char*)d_ws;
    auto alloc = [&](size_t bytes) -> char* {
        char* r = p;
        p += (bytes + 255) & ~size_t(255);
        return r;
    };
    unsigned short* Wtbuf = (unsigned short*)alloc((size_t)8 * 16384 * 2);
    unsigned short* K0 = (unsigned short*)alloc((size_t)n0 * NDIM * 2);
    unsigned short* Q0 = (unsigned short*)alloc((size_t)n0 * NDIM * 2);
    unsigned short* V0 = (unsigned short*)alloc((size_t)n0 * NDIM * 2);
    unsigned short* K1 = (unsigned short*)alloc((size_t)n1 * NDIM * 2);
    unsigned short* Q1 = (unsigned short*)alloc((size_t)n1 * NDIM * 2);
    unsigned short* V1 = (unsigned short*)alloc((size_t)n1 * NDIM * 2);
    unsigned short* aggb1  = (unsigned short*)alloc((size_t)n1 * NDIM * 2);
    unsigned short* aggb0a = (unsigned short*)alloc((size_t)n0 * NDIM * 2);
    unsigned short* aggb0b = (unsigned short*)alloc((size_t)n0 * NDIM * 2);
    int* off0 = (int*)alloc((size_t)(n1 + 1) * 4);
    int* off1 = (int*)alloc((size_t)(n0 + 1) * 4);
    int* off2 = (int*)alloc((size_t)(n0 + 1) * 4);
    int* rcur = (int*)alloc((size_t)128 * 4);
    int* cnts = (int*)alloc((size_t)3 * UNITS * NRNG * 4);
    uint2* stg = (uint2*)alloc((size_t)3 * NRNG * cap * 8);
    unsigned int* edg0 = (unsigned int*)alloc((size_t)E0 * 4);
    unsigned int* edg1 = (unsigned int*)alloc((size_t)E1 * 4);
    unsigned int* edg2 = (unsigned int*)alloc((size_t)E2 * 4);

    dim3 blk(256);
    const int blocks0 = (n0 + 63) / 64, blocks1 = (n1 + 63) / 64;

    wt_prep<<<8, 256, 0, stream>>>(Kw, Qw, Vw, Aw, Wtbuf);
    gemm_kqv<<<blocks0 + blocks1, blk, 0, stream>>>(feat0, feat1, Wtbuf, Kb, Qb, Vb,
                                                    K0, Q0, V0, K1, Q1, V1, n0, n1, blocks0);

    bucket_count<<<dim3(NBK, 3), blk, 0, stream>>>(dst0, E0, dst1, E1, dst2, E2, n0, n1, cnts);
    bucket_scan<<<3 * NRNG, blk, 0, stream>>>(cnts, rcur);
    bucket_write<<<dim3(NBK, 3), blk, 0, stream>>>(dst0, src0, ev0, E0,
                                                   dst1, src1, ev1, E1,
                                                   dst2, src2, ev2, E2,
                                                   n0, n1, ew, eb, cnts, stg, cap);
    sortB<<<dim3(NRNG, 3), 1024, 0, stream>>>(stg, cap, rcur,
                                              n1, off0, edg0,
                                              n0, off1, edg1,
                                              n0, off2, edg2);

    const int nmax = (n0 > n1) ? n0 : n1;
    const int ebx = ((nmax + 1) / 2 + 3) / 4;
    edge_agg3<<<dim3(ebx, 3), blk, 0, stream>>>(
        off0, edg0, K0, Q1, V0, aggb1, n1,
        off1, edg1, K1, Q0, V1, aggb0a, n0,
        off2, edg2, K0, Q0, V0, aggb0b, n0);

    gemm_out<<<blocks0 + blocks1, blk, 0, stream>>>(aggb0a, aggb0b, aggb1, Wtbuf, Ab,
                                                    feat0, feat1, skip, (float*)d_out,
                                                    n0, n1, blocks0);
}